// Round 4
// baseline (114.978 us; speedup 1.0000x reference)
//
#include <hip/hip_runtime.h>
#include <hip/hip_bf16.h>
#include <stdint.h>

#define B_    4
#define N_    8192
#define K_    32
#define CX    67      // 3 + C_IN
#define CMID  64
#define COUT  128

#define CSTR  100     // Xs chan stride (>=96, staging writes 4-wayish, b64 reads ~free)
#define HSTR  72      // Hbuf chan stride (mult of 8 for b128-aligned reads)
#define TPG   8       // n-groups per WG (each group = 4 n, one per wave); must be even
#define NWG   1024
#define GMAX  8191

typedef __bf16 bf16_t;
typedef bf16_t bf16x8 __attribute__((ext_vector_type(8)));
typedef bf16_t bf16x4 __attribute__((ext_vector_type(4)));
typedef float  f32x4  __attribute__((ext_vector_type(4)));

__device__ __forceinline__ uint32_t pack2bf(float a, float b) {
    union { bf16_t h[2]; uint32_t u; } x;
    x.h[0] = (bf16_t)a; x.h[1] = (bf16_t)b;
    return x.u;
}

template<bool DIRECT>
__global__ __launch_bounds__(256, 2)
void sa_main(const float* __restrict__ dp, const float* __restrict__ fj,
             const float* __restrict__ W1, const float* __restrict__ b1,
             const float* __restrict__ W2, const float* __restrict__ b2,
             float* __restrict__ dst)
{
    // LDS: Xs 4*32*CSTR (25600B) + Hb 4*16*HSTR (9216B) = 34816B
    __shared__ bf16_t smem[4 * 32 * CSTR + 4 * 16 * HSTR];

    const int tid  = threadIdx.x;
    const int wave = tid >> 6;
    const int lane = tid & 63;
    const int lrow = lane & 15;   // MFMA row/col index within 16-tile
    const int g    = lane >> 4;   // 16-lane group

    bf16_t* Xw = smem + wave * 32 * CSTR;
    bf16_t* Hw = smem + 4 * 32 * CSTR + wave * 16 * HSTR;

    const size_t plane = (size_t)N_ * K_;
    const int cr = lane >> 3;            // staging: channel-in-group 0..7
    const int k0 = (lane & 7) << 2;      // staging: k base 0..28

    // ---- slim issuer: one dp/fj select (j=0), one clamp (j=8), uniform middle ----
    auto issue = [&](float4 (&v)[9], int Gi) {
        const int bb = Gi >> 11;
        const int nn = ((Gi & 2047) << 2) + wave;
        const size_t rbase = (size_t)nn * K_ + k0;
        const float* fp  = fj + (size_t)bb * 64 * plane + rbase;   // fj channel c' = c-3
        const float* dp0 = dp + (size_t)bb * 3  * plane + rbase;
        const float* p0 = (cr < 3) ? dp0 + (size_t)cr * plane
                                   : fp  + (size_t)(cr - 3) * plane;
        v[0] = *(const float4*)p0;
        const float* pj = fp + (size_t)(8 + cr - 3) * plane;
        #pragma unroll
        for (int j = 1; j < 8; ++j) {
            v[j] = *(const float4*)pj;
            pj += 8 * plane;
        }
        const int c8 = (cr < 3) ? (64 + cr) : 66;   // clamp: line already fetched
        v[8] = *(const float4*)(fp + (size_t)(c8 - 3) * plane);
    };

    // ---- 2-deep prefetch: issue G0, G0+1 before the weight prologue ----
    float4 va[9], vb[9];
    {
        const int G0 = blockIdx.x * TPG;
        issue(va, G0);
        issue(vb, G0 + 1 > GMAX ? GMAX : G0 + 1);
    }

    // ---- prologue: W1 frags via transient LDS stage (aliased into Xs area) ----
    for (int i = tid; i < 64 * 96; i += 256) {
        int o = i / 96, c = i - o * 96;
        smem[i] = (c < CX) ? (bf16_t)W1[o * CX + c] : (bf16_t)0.f;
    }
    __syncthreads();
    bf16x8 w1f[3][4];
    #pragma unroll
    for (int kc = 0; kc < 3; ++kc)
        #pragma unroll
        for (int rt = 0; rt < 4; ++rt)
            w1f[kc][rt] = *(const bf16x8*)&smem[(rt * 16 + lrow) * 96 + kc * 32 + g * 8];
    __syncthreads();
    // W2 frags (B operand of the swapped layer-2 MFMA)
    for (int i = tid; i < 128 * 72; i += 256) {
        int o = i / 72, c = i - o * 72;
        smem[i] = (c < CMID) ? (bf16_t)W2[o * CMID + c] : (bf16_t)0.f;
    }
    __syncthreads();
    bf16x8 w2f[2][8];
    #pragma unroll
    for (int kc = 0; kc < 2; ++kc)
        #pragma unroll
        for (int ot = 0; ot < 8; ++ot)
            w2f[kc][ot] = *(const bf16x8*)&smem[(ot * 16 + lrow) * 72 + kc * 32 + g * 8];
    __syncthreads();
    // zero Xs region (pad chans 67..95 stay zero forever; 0..66 rewritten each iter)
    for (int i = tid; i < 4 * 32 * CSTR; i += 256) smem[i] = (bf16_t)0.f;
    __syncthreads();

    f32x4 b1f[4];
    #pragma unroll
    for (int rt = 0; rt < 4; ++rt) b1f[rt] = *(const f32x4*)(b1 + rt * 16 + g * 4);
    float b2f[8];
    #pragma unroll
    for (int ot = 0; ot < 8; ++ot) b2f[ot] = b2[ot * 16 + lrow];

    // ---- one point: stage v -> reissue v for G+2 -> compute -> store ----
    auto point = [&](float4 (&v)[9], int G) {
        const int b = G >> 11;
        const int n = ((G & 2047) << 2) + wave;

        // stage current v -> Xw (consumes v)
        #pragma unroll
        for (int j = 0; j < 9; ++j) {
            int c = j * 8 + cr;
            if (c < CX) {
                Xw[(k0 + 0) * CSTR + c] = (bf16_t)v[j].x;
                Xw[(k0 + 1) * CSTR + c] = (bf16_t)v[j].y;
                Xw[(k0 + 2) * CSTR + c] = (bf16_t)v[j].z;
                Xw[(k0 + 3) * CSTR + c] = (bf16_t)v[j].w;
            }
        }
        // reissue this buffer for G+2 (stays in flight across the next point too)
        {
            int Gn = G + 2;
            if (Gn > GMAX) Gn = GMAX;
            issue(v, Gn);
        }

        float macc[8];
        #pragma unroll
        for (int i = 0; i < 8; ++i) macc[i] = -3e38f;

        #pragma unroll
        for (int ct = 0; ct < 2; ++ct) {
            const int col = ct * 16 + lrow;
            // layer 1: acc1 = W1 * X
            f32x4 acc1[4] = {};
            __builtin_amdgcn_s_setprio(1);
            #pragma unroll
            for (int kc = 0; kc < 3; ++kc) {
                bf16x4 lo = *(const bf16x4*)&Xw[col * CSTR + kc * 32 + g * 8];
                bf16x4 hi = *(const bf16x4*)&Xw[col * CSTR + kc * 32 + g * 8 + 4];
                bf16x8 bfX = __builtin_shufflevector(lo, hi, 0, 1, 2, 3, 4, 5, 6, 7);
                #pragma unroll
                for (int rt = 0; rt < 4; ++rt)
                    acc1[rt] = __builtin_amdgcn_mfma_f32_16x16x32_bf16(w1f[kc][rt], bfX, acc1[rt], 0, 0, 0);
            }
            __builtin_amdgcn_s_setprio(0);
            // epilogue 1: bias+relu -> packed bf16 -> Hw (wave-private)
            #pragma unroll
            for (int rt = 0; rt < 4; ++rt) {
                float h0 = fmaxf(acc1[rt][0] + b1f[rt][0], 0.f);
                float h1 = fmaxf(acc1[rt][1] + b1f[rt][1], 0.f);
                float h2 = fmaxf(acc1[rt][2] + b1f[rt][2], 0.f);
                float h3 = fmaxf(acc1[rt][3] + b1f[rt][3], 0.f);
                *(uint2*)&Hw[lrow * HSTR + rt * 16 + g * 4] =
                    make_uint2(pack2bf(h0, h1), pack2bf(h2, h3));
            }
            // layer 2 (operands swapped => D rows = k-positions)
            bf16x8 hb0 = *(const bf16x8*)&Hw[lrow * HSTR +  0 + g * 8];
            bf16x8 hb1 = *(const bf16x8*)&Hw[lrow * HSTR + 32 + g * 8];
            __builtin_amdgcn_s_setprio(1);
            #pragma unroll
            for (int bt = 0; bt < 2; ++bt) {
                f32x4 a2[4] = {};
                #pragma unroll
                for (int o = 0; o < 4; ++o) {
                    a2[o] = __builtin_amdgcn_mfma_f32_16x16x32_bf16(hb0, w2f[0][bt * 4 + o], a2[o], 0, 0, 0);
                    a2[o] = __builtin_amdgcn_mfma_f32_16x16x32_bf16(hb1, w2f[1][bt * 4 + o], a2[o], 0, 0, 0);
                }
                #pragma unroll
                for (int o = 0; o < 4; ++o) {
                    float m = fmaxf(fmaxf(a2[o][0], a2[o][1]), fmaxf(a2[o][2], a2[o][3]));
                    macc[bt * 4 + o] = fmaxf(macc[bt * 4 + o], m);
                }
            }
            __builtin_amdgcn_s_setprio(0);
        }

        // cross-group pool (xor16 + xor32), bias, relu
        #pragma unroll
        for (int ot = 0; ot < 8; ++ot) {
            float vv = macc[ot];
            vv = fmaxf(vv, __shfl_xor(vv, 16, 64));
            vv = fmaxf(vv, __shfl_xor(vv, 32, 64));
            macc[ot] = fmaxf(vv + b2f[ot], 0.f);
        }
        float oa = (g == 0) ? macc[0] : (g == 1) ? macc[2] : (g == 2) ? macc[4] : macc[6];
        float ob = (g == 0) ? macc[1] : (g == 1) ? macc[3] : (g == 2) ? macc[5] : macc[7];
        const int ca = g * 32 + lrow;
        const int cb = g * 32 + 16 + lrow;
        if (DIRECT) {
            float* op = dst + (size_t)b * COUT * N_ + n;
            op[(size_t)ca * N_] = oa;
            op[(size_t)cb * N_] = ob;
        } else {
            float* wp = dst + ((size_t)(b * N_ + n)) * COUT;   // ws[b][n][c]
            wp[ca] = oa;
            wp[cb] = ob;
        }
    };

    #pragma unroll 1
    for (int t = 0; t < TPG; t += 2) {
        const int G = blockIdx.x * TPG + t;
        point(va, G);
        point(vb, G + 1);
    }
}

// ws[b][n][c] -> out[b][c][n], full lines on both sides
__global__ __launch_bounds__(256)
void sa_transpose(const float* __restrict__ ws, float* __restrict__ out)
{
    __shared__ float tile[32][136];
    const int t  = threadIdx.x;
    const int i  = blockIdx.x;         // 0..1023
    const int b  = i >> 8;
    const int n0 = (i & 255) << 5;

    const float* rp = ws + ((size_t)(b * N_ + n0)) * COUT;
    #pragma unroll
    for (int r = 0; r < 4; ++r) {
        int flat = (r * 256 + t) * 4;
        int nl = flat >> 7, c = flat & 127;
        float4 v = *(const float4*)(rp + (size_t)nl * COUT + c);
        *(float4*)&tile[nl][c] = v;
    }
    __syncthreads();
    float* op = out + (size_t)b * COUT * N_ + n0;
    const int nl4 = (t & 7) << 2;
    #pragma unroll
    for (int r2 = 0; r2 < 4; ++r2) {
        int c = r2 * 32 + (t >> 3);
        float4 o4;
        o4.x = tile[nl4 + 0][c];
        o4.y = tile[nl4 + 1][c];
        o4.z = tile[nl4 + 2][c];
        o4.w = tile[nl4 + 3][c];
        *(float4*)(op + (size_t)c * N_ + nl4) = o4;
    }
}

extern "C" void kernel_launch(void* const* d_in, const int* in_sizes, int n_in,
                              void* d_out, int out_size, void* d_ws, size_t ws_size,
                              hipStream_t stream) {
    // inputs: 0=p (unused), 1=f (unused), 2=dp, 3=fj, 4=W1, 5=b1, 6=W2, 7=b2
    const float* dp = (const float*)d_in[2];
    const float* fj = (const float*)d_in[3];
    const float* W1 = (const float*)d_in[4];
    const float* b1 = (const float*)d_in[5];
    const float* W2 = (const float*)d_in[6];
    const float* b2 = (const float*)d_in[7];
    float* out = (float*)d_out;

    const size_t ws_need = (size_t)B_ * N_ * COUT * sizeof(float);
    if (ws_size >= ws_need) {
        float* ws = (float*)d_ws;
        hipLaunchKernelGGL((sa_main<false>), dim3(NWG), dim3(256), 0, stream,
                           dp, fj, W1, b1, W2, b2, ws);
        hipLaunchKernelGGL(sa_transpose, dim3(1024), dim3(256), 0, stream, ws, out);
    } else {
        hipLaunchKernelGGL((sa_main<true>), dim3(NWG), dim3(256), 0, stream,
                           dp, fj, W1, b1, W2, b2, out);
    }
}